// Round 11
// baseline (5168.128 us; speedup 1.0000x reference)
//
#include <hip/hip_runtime.h>
#include <stdint.h>

// RNN LM: embed->shift -> 2-layer tanh RNN (T=2048) -> logits vs embedding^T
//         -> log_softmax -> gather at tokens -> sum (scalar out).
//
// k_rnn R11: R6 EXACT skeleton (f32 canary dataflow, DPP-ring dots, s_barrier
// combine, 16-finalist finalize) + depth-2 pipelined polling done SAFELY:
// the whole poll loop lives in ONE asm block (issue, counted vmcnt, check,
// branch, drain all inside), so register allocation cannot break the
// in-flight-load -> register binding (the R7 failure). Two samples always in
// flight -> detect cadence ~RT/2 instead of ~RT.
//  - all-lanes-ready check: v_cmp_ne_u32 + s_and_b64 chain, then
//    s_andn2_b64 exec-based test + s_cbranch.
//  - exits drain vmcnt(0); via-B exit copies B->A after the drain (no
//    same-address load-ordering assumption).

#define TSEQ 2048
#define NVOCAB 32000
#define DEMB 512
#define DHID 1024
#define CAN 0xFFFFFFFFu

typedef __attribute__((ext_vector_type(8))) short short8;
typedef __attribute__((ext_vector_type(4))) float f32x4;
typedef __attribute__((ext_vector_type(2))) float f32x2;

__device__ __forceinline__ unsigned short f2bf(float f) {
  union { float f; unsigned u; } v; v.f = f;
  unsigned r = (v.u + 0x7FFFu + ((v.u >> 16) & 1u)) >> 16;
  return (unsigned short)r;
}

// Depth-2 pipelined canary poll of 4 consecutive dwords at p.
// Entire loop in one asm block: invariant at loop head = one 4-load sample
// in flight. vmcnt(4) waits exactly the older sample (in-order retirement;
// any pre-existing older stores retire first). All exits drain vmcnt(0).
__device__ __forceinline__ void poll_l1(const float* p, f32x4& h) {
  float a0, a1, a2, a3, b0, b1, b2, b3;
  unsigned long long m;
  asm volatile(
      "global_load_dword %0, %9, off sc0 sc1\n\t"
      "global_load_dword %1, %9, off offset:4 sc0 sc1\n\t"
      "global_load_dword %2, %9, off offset:8 sc0 sc1\n\t"
      "global_load_dword %3, %9, off offset:12 sc0 sc1\n\t"
      "1:\n\t"
      "global_load_dword %4, %9, off sc0 sc1\n\t"
      "global_load_dword %5, %9, off offset:4 sc0 sc1\n\t"
      "global_load_dword %6, %9, off offset:8 sc0 sc1\n\t"
      "global_load_dword %7, %9, off offset:12 sc0 sc1\n\t"
      "s_waitcnt vmcnt(4)\n\t"            // sample A arrived
      "v_cmp_ne_u32 vcc, -1, %0\n\t"
      "s_mov_b64 %8, vcc\n\t"
      "v_cmp_ne_u32 vcc, -1, %1\n\t"
      "s_and_b64 %8, %8, vcc\n\t"
      "v_cmp_ne_u32 vcc, -1, %2\n\t"
      "s_and_b64 %8, %8, vcc\n\t"
      "v_cmp_ne_u32 vcc, -1, %3\n\t"
      "s_and_b64 %8, %8, vcc\n\t"
      "s_andn2_b64 %8, exec, %8\n\t"      // 0 <=> all active lanes ready
      "s_cbranch_scc0 3f\n\t"             // exit via A
      "global_load_dword %0, %9, off sc0 sc1\n\t"
      "global_load_dword %1, %9, off offset:4 sc0 sc1\n\t"
      "global_load_dword %2, %9, off offset:8 sc0 sc1\n\t"
      "global_load_dword %3, %9, off offset:12 sc0 sc1\n\t"
      "s_waitcnt vmcnt(4)\n\t"            // sample B arrived
      "v_cmp_ne_u32 vcc, -1, %4\n\t"
      "s_mov_b64 %8, vcc\n\t"
      "v_cmp_ne_u32 vcc, -1, %5\n\t"
      "s_and_b64 %8, %8, vcc\n\t"
      "v_cmp_ne_u32 vcc, -1, %6\n\t"
      "s_and_b64 %8, %8, vcc\n\t"
      "v_cmp_ne_u32 vcc, -1, %7\n\t"
      "s_and_b64 %8, %8, vcc\n\t"
      "s_andn2_b64 %8, exec, %8\n\t"
      "s_cbranch_scc1 1b\n\t"             // not ready -> loop (A in flight)
      "s_waitcnt vmcnt(0)\n\t"            // exit via B: drain A, then copy
      "v_mov_b32 %0, %4\n\t"
      "v_mov_b32 %1, %5\n\t"
      "v_mov_b32 %2, %6\n\t"
      "v_mov_b32 %3, %7\n\t"
      "s_branch 4f\n\t"
      "3:\n\t"
      "s_waitcnt vmcnt(0)\n\t"            // exit via A: drain B
      "4:"
      : "=&v"(a0), "=&v"(a1), "=&v"(a2), "=&v"(a3),
        "=&v"(b0), "=&v"(b1), "=&v"(b2), "=&v"(b3), "=&s"(m)
      : "v"(p)
      : "vcc", "scc", "memory");
  h.x = a0; h.y = a1; h.z = a2; h.w = a3;
}

// Depth-2 pipelined poll: 4 dwords at pa + 2 dwords at pb (6 per sample).
__device__ __forceinline__ void poll_l2(const float* pa, const float* pb,
                                        f32x4& hq, f32x2& hp) {
  float a0, a1, a2, a3, a4, a5, b0, b1, b2, b3, b4, b5;
  unsigned long long m;
  asm volatile(
      "global_load_dword %0, %13, off sc0 sc1\n\t"
      "global_load_dword %1, %13, off offset:4 sc0 sc1\n\t"
      "global_load_dword %2, %13, off offset:8 sc0 sc1\n\t"
      "global_load_dword %3, %13, off offset:12 sc0 sc1\n\t"
      "global_load_dword %4, %14, off sc0 sc1\n\t"
      "global_load_dword %5, %14, off offset:4 sc0 sc1\n\t"
      "1:\n\t"
      "global_load_dword %6, %13, off sc0 sc1\n\t"
      "global_load_dword %7, %13, off offset:4 sc0 sc1\n\t"
      "global_load_dword %8, %13, off offset:8 sc0 sc1\n\t"
      "global_load_dword %9, %13, off offset:12 sc0 sc1\n\t"
      "global_load_dword %10, %14, off sc0 sc1\n\t"
      "global_load_dword %11, %14, off offset:4 sc0 sc1\n\t"
      "s_waitcnt vmcnt(6)\n\t"            // sample A arrived
      "v_cmp_ne_u32 vcc, -1, %0\n\t"
      "s_mov_b64 %12, vcc\n\t"
      "v_cmp_ne_u32 vcc, -1, %1\n\t"
      "s_and_b64 %12, %12, vcc\n\t"
      "v_cmp_ne_u32 vcc, -1, %2\n\t"
      "s_and_b64 %12, %12, vcc\n\t"
      "v_cmp_ne_u32 vcc, -1, %3\n\t"
      "s_and_b64 %12, %12, vcc\n\t"
      "v_cmp_ne_u32 vcc, -1, %4\n\t"
      "s_and_b64 %12, %12, vcc\n\t"
      "v_cmp_ne_u32 vcc, -1, %5\n\t"
      "s_and_b64 %12, %12, vcc\n\t"
      "s_andn2_b64 %12, exec, %12\n\t"
      "s_cbranch_scc0 3f\n\t"             // exit via A
      "global_load_dword %0, %13, off sc0 sc1\n\t"
      "global_load_dword %1, %13, off offset:4 sc0 sc1\n\t"
      "global_load_dword %2, %13, off offset:8 sc0 sc1\n\t"
      "global_load_dword %3, %13, off offset:12 sc0 sc1\n\t"
      "global_load_dword %4, %14, off sc0 sc1\n\t"
      "global_load_dword %5, %14, off offset:4 sc0 sc1\n\t"
      "s_waitcnt vmcnt(6)\n\t"            // sample B arrived
      "v_cmp_ne_u32 vcc, -1, %6\n\t"
      "s_mov_b64 %12, vcc\n\t"
      "v_cmp_ne_u32 vcc, -1, %7\n\t"
      "s_and_b64 %12, %12, vcc\n\t"
      "v_cmp_ne_u32 vcc, -1, %8\n\t"
      "s_and_b64 %12, %12, vcc\n\t"
      "v_cmp_ne_u32 vcc, -1, %9\n\t"
      "s_and_b64 %12, %12, vcc\n\t"
      "v_cmp_ne_u32 vcc, -1, %10\n\t"
      "s_and_b64 %12, %12, vcc\n\t"
      "v_cmp_ne_u32 vcc, -1, %11\n\t"
      "s_and_b64 %12, %12, vcc\n\t"
      "s_andn2_b64 %12, exec, %12\n\t"
      "s_cbranch_scc1 1b\n\t"             // not ready -> loop
      "s_waitcnt vmcnt(0)\n\t"            // exit via B: drain A, copy B->A
      "v_mov_b32 %0, %6\n\t"
      "v_mov_b32 %1, %7\n\t"
      "v_mov_b32 %2, %8\n\t"
      "v_mov_b32 %3, %9\n\t"
      "v_mov_b32 %4, %10\n\t"
      "v_mov_b32 %5, %11\n\t"
      "s_branch 4f\n\t"
      "3:\n\t"
      "s_waitcnt vmcnt(0)\n\t"            // exit via A: drain B
      "4:"
      : "=&v"(a0), "=&v"(a1), "=&v"(a2), "=&v"(a3), "=&v"(a4), "=&v"(a5),
        "=&v"(b0), "=&v"(b1), "=&v"(b2), "=&v"(b3), "=&v"(b4), "=&v"(b5),
        "=&s"(m)
      : "v"(pa), "v"(pb)
      : "vcc", "scc", "memory");
  hq.x = a0; hq.y = a1; hq.z = a2; hq.w = a3;
  hp.x = a4; hp.y = a5;
}

__device__ __forceinline__ void llc_st4(float* p, float v) {
  asm volatile("global_store_dword %0, %1, off sc0 sc1" :: "v"(p), "v"(v) : "memory");
}

// rotate right by 1 lane within each 16-lane row (row_ror:1 = 0x121)
__device__ __forceinline__ f32x4 rotq(f32x4 h) {
  f32x4 r;
  r.x = __int_as_float(__builtin_amdgcn_mov_dpp(__float_as_int(h.x), 0x121, 0xf, 0xf, false));
  r.y = __int_as_float(__builtin_amdgcn_mov_dpp(__float_as_int(h.y), 0x121, 0xf, 0xf, false));
  r.z = __int_as_float(__builtin_amdgcn_mov_dpp(__float_as_int(h.z), 0x121, 0xf, 0xf, false));
  r.w = __int_as_float(__builtin_amdgcn_mov_dpp(__float_as_int(h.w), 0x121, 0xf, 0xf, false));
  return r;
}
__device__ __forceinline__ f32x2 rotp(f32x2 h) {
  f32x2 r;
  r.x = __int_as_float(__builtin_amdgcn_mov_dpp(__float_as_int(h.x), 0x121, 0xf, 0xf, false));
  r.y = __int_as_float(__builtin_amdgcn_mov_dpp(__float_as_int(h.y), 0x121, 0xf, 0xf, false));
  return r;
}

__device__ __forceinline__ float tanh_fast(float x) {
  float ax = fabsf(x);
  float e = __expf(ax + ax);
  float t = 1.f - __fdividef(2.f, e + 1.f);
  return (x < 0.f) ? -t : t;
}

// ---------------- init: poison all slots; row 0 = real zeros ----------------
__global__ void k_init(uint4* __restrict__ h1v4, uint4* __restrict__ h2v4) {
  const int n1 = (TSEQ + 1) * DHID / 4;
  const int n2 = (TSEQ + 1) * DEMB / 4;
  uint4 can; can.x = CAN; can.y = CAN; can.z = CAN; can.w = CAN;
  uint4 zer; zer.x = 0u; zer.y = 0u; zer.z = 0u; zer.w = 0u;
  const int stride = gridDim.x * blockDim.x;
  for (int i = blockIdx.x * blockDim.x + threadIdx.x; i < n1 + n2; i += stride) {
    if (i < n1) {
      h1v4[i] = (i < DHID / 4) ? zer : can;
    } else {
      int j = i - n1;
      h2v4[j] = (j < DEMB / 4) ? zer : can;
    }
  }
}

// ---------------- xW1[t][j] = b1[j] + sum_e inputs[t][e]*W1[e][j] ------------
__global__ __launch_bounds__(256) void k_xw1(const int* __restrict__ tok,
                                             const float* __restrict__ emb,
                                             const float* __restrict__ W1,
                                             const float* __restrict__ b1,
                                             float* __restrict__ xW1) {
  __shared__ float in_lds[16 * DEMB];
  const int tid = threadIdx.x;
  const int rb = blockIdx.x >> 2, cb = blockIdx.x & 3;
  const int t0 = rb * 16, j0 = cb * 256;
  for (int idx = tid; idx < 16 * 128; idx += 256) {
    int r = idx >> 7, q = idx & 127;
    int t = t0 + r;
    float4 v;
    if (t == 0) { v.x = 0.f; v.y = 0.f; v.z = 0.f; v.w = 0.f; }
    else        { v = *(const float4*)(emb + (size_t)tok[t - 1] * DEMB + q * 4); }
    *(float4*)&in_lds[r * DEMB + q * 4] = v;
  }
  __syncthreads();
  const int j = j0 + tid;
  float acc[16];
  {
    float bb = b1[j];
#pragma unroll
    for (int r = 0; r < 16; ++r) acc[r] = bb;
  }
  for (int k = 0; k < DEMB; k += 4) {
    const float* wp = W1 + (size_t)k * DHID + j;
    float w0 = wp[0], w1 = wp[DHID], w2 = wp[2 * DHID], w3 = wp[3 * DHID];
#pragma unroll
    for (int r = 0; r < 16; ++r) {
      float4 h = *(const float4*)&in_lds[r * DEMB + k];
      acc[r] += h.x * w0;
      acc[r] += h.y * w1;
      acc[r] += h.z * w2;
      acc[r] += h.w * w3;
    }
  }
#pragma unroll
  for (int r = 0; r < 16; ++r) xW1[(size_t)(t0 + r) * DHID + j] = acc[r];
}

// ---------------- persistent RNN ----------------
// 96 WGs x 256 thr. WG 0..63: layer1 (16 cols). WG 64..95: layer2 (16 cols).
__global__ __launch_bounds__(256, 1) void k_rnn(const float* __restrict__ xW1,
                                                const float* __restrict__ U1,
                                                const float* __restrict__ W2,
                                                const float* __restrict__ U2,
                                                const float* __restrict__ b2,
                                                float* __restrict__ h1v,
                                                float* __restrict__ h2v,
                                                float* __restrict__ h2buf) {
  __shared__ float cmb[2][128];   // [parity][col*8 + wave]
  const int tid = threadIdx.x;
  const int wg = blockIdx.x;
  const int l = tid & 63, w = tid >> 6;
  const int r = l >> 4, i = l & 15;

  if (wg < 64) {  // ---- layer 1: h1[t] = tanh(xW1[t] + h1[t-1]@U1) ----
    const int c0 = wg * 16;
    // wA[4j+e] = U1[256w + 64r + 4*((i-j)&15) + e][c0+i]
    float wA[64];
#pragma unroll
    for (int j = 0; j < 16; ++j) {
      int sl = (i - j) & 15;
      const float* up = U1 + (size_t)(256 * w + 64 * r + 4 * sl) * DHID + c0 + i;
#pragma unroll
      for (int e = 0; e < 4; ++e) wA[4 * j + e] = up[(size_t)e * DHID];
    }
    const float* pp = h1v + 4 * tid;              // poll row st (st=0 -> zeros)
    const float* xp = xW1 + c0 + (tid & 15);      // finalists (tid<16)
    float* stp = h1v + DHID + c0 + tid;           // store row st+1 (tid<16)
    for (int st = 0; st < TSEQ; ++st) {
      float xv = *xp;                             // early, independent
      f32x4 h;
      poll_l1(pp, h);
      f32x4 ac = (f32x4)(0.f);
#pragma unroll
      for (int j = 0; j < 16; ++j) {
        ac.x += h.x * wA[4 * j + 0];
        ac.y += h.y * wA[4 * j + 1];
        ac.z += h.z * wA[4 * j + 2];
        ac.w += h.w * wA[4 * j + 3];
        if (j < 15) h = rotq(h);
      }
      float a = (ac.x + ac.y) + (ac.z + ac.w);
      a += __shfl_xor(a, 16);
      a += __shfl_xor(a, 32);
      const int par = st & 1;
      if (l < 16) cmb[par][i * 8 + w] = a;
      __syncthreads();
      if (tid < 16) {
        f32x4 c4 = *(const f32x4*)&cmb[par][tid * 8];
        float hv = tanh_fast(xv + ((c4.x + c4.y) + (c4.z + c4.w)));
        llc_st4(stp, hv);
      }
      pp += DHID; xp += DHID; stp += DHID;
    }
  } else {  // ---- layer 2: h2[t] = tanh(h1[t]@W2 + h2[t-1]@U2 + b2) ----
    const int c0 = (wg - 64) * 16;
    // quad-ring (W2, 64 k of h1) + pair-ring (U2, 32 k of h2prev)
    float wq[64], wp[32];
#pragma unroll
    for (int j = 0; j < 16; ++j) {
      int sl = (i - j) & 15;
      const float* m = W2 + (size_t)(256 * w + 64 * r + 4 * sl) * DEMB + c0 + i;
#pragma unroll
      for (int e = 0; e < 4; ++e) wq[4 * j + e] = m[(size_t)e * DEMB];
      const float* u = U2 + (size_t)(128 * w + 32 * r + 2 * sl) * DEMB + c0 + i;
      wp[2 * j + 0] = u[0];
      wp[2 * j + 1] = u[DEMB];
    }
    const float bias = b2[c0 + (tid & 15)];
    const float* ppA = h1v + DHID + 256 * w + 64 * r + 4 * i;  // h1[t] = row t+1
    const float* ppB = h2v + 128 * w + 32 * r + 2 * i;         // h2[t-1] = row t
    float* stp = h2v + DEMB + c0 + tid;                        // row t+1 (tid<16)
    float* hb = h2buf + DEMB + c0 + tid;
    for (int t = 0; t < TSEQ; ++t) {
      f32x4 hq; f32x2 hp;
      poll_l2(ppA, ppB, hq, hp);
      f32x4 aq = (f32x4)(0.f);
      f32x2 ap = (f32x2)(0.f);
#pragma unroll
      for (int j = 0; j < 16; ++j) {
        aq.x += hq.x * wq[4 * j + 0];
        aq.y += hq.y * wq[4 * j + 1];
        aq.z += hq.z * wq[4 * j + 2];
        aq.w += hq.w * wq[4 * j + 3];
        ap.x += hp.x * wp[2 * j + 0];
        ap.y += hp.y * wp[2 * j + 1];
        if (j < 15) { hq = rotq(hq); hp = rotp(hp); }
      }
      float a = ((aq.x + aq.y) + (aq.z + aq.w)) + (ap.x + ap.y);
      a += __shfl_xor(a, 16);
      a += __shfl_xor(a, 32);
      const int par = t & 1;
      if (l < 16) cmb[par][i * 8 + w] = a;
      __syncthreads();
      if (tid < 16) {
        f32x4 c4 = *(const f32x4*)&cmb[par][tid * 8];
        float hv = tanh_fast(bias + ((c4.x + c4.y) + (c4.z + c4.w)));
        llc_st4(stp, hv);
        *hb = hv;
      }
      ppA += DHID; ppB += DEMB; stp += DEMB; hb += DEMB;
    }
  }
}

// ---------------- f32 -> bf16 casts (embedding + h2 history) ----------------
__global__ void k_conv(const float* __restrict__ emb, const float* __restrict__ h2f,
                       unsigned short* __restrict__ embB, unsigned short* __restrict__ h2b) {
  const int n1 = NVOCAB * DEMB / 4;
  const int n2 = TSEQ * DEMB / 4;
  const int stride = gridDim.x * blockDim.x;
  for (int i = blockIdx.x * blockDim.x + threadIdx.x; i < n1 + n2; i += stride) {
    float4 v;
    if (i < n1) v = ((const float4*)emb)[i];
    else        v = ((const float4*)h2f)[i - n1];
    ushort4 o;
    o.x = f2bf(v.x); o.y = f2bf(v.y); o.z = f2bf(v.z); o.w = f2bf(v.w);
    if (i < n1) ((ushort4*)embB)[i] = o;
    else        ((ushort4*)h2b)[i - n1] = o;
  }
}

// ---------------- fused logits GEMM + online softmax stats ----------------
__global__ __launch_bounds__(256, 1) void k_logits(const unsigned short* __restrict__ Ab,
                                                   const unsigned short* __restrict__ Bb,
                                                   float* __restrict__ pmax,
                                                   float* __restrict__ psum) {
  extern __shared__ char smem_dyn[];
  unsigned short* As = (unsigned short*)smem_dyn;       // 128*512*2 = 131072 B
  float* sstat = (float*)(smem_dyn + 131072);           // 4*128*2 f32
  const int tid = threadIdx.x;
  const int rb = blockIdx.x >> 4, ch = blockIdx.x & 15;
  const int r0 = rb * 128, v0 = ch * 2000;
  for (int idx = tid; idx < 128 * 64; idx += 256) {
    int row = idx >> 6, kq = idx & 63;
    uint4 v = *(const uint4*)(Ab + (size_t)(r0 + row) * DEMB + kq * 8);
    int byte = (row * 1024 + kq * 16) ^ ((row & 7) << 4);
    *(uint4*)((char*)As + byte) = v;
  }
  __syncthreads();
  const int wv = tid >> 6, lane = tid & 63;
  const int col = lane & 15, kg = lane >> 4;
  f32x4 rmax[8], rsum[8];
#pragma unroll
  for (int t = 0; t < 8; ++t) { rmax[t] = (f32x4)(-3.0e38f); rsum[t] = (f32x4)(0.f); }

  for (int strip = wv; strip < 125; strip += 4) {
    const unsigned short* bp = Bb + (size_t)(v0 + strip * 16 + col) * DEMB + kg * 8;
    f32x4 acc[8];
#pragma unroll
    for (int t = 0; t < 8; ++t) acc[t] = (f32x4)(0.f);
#pragma unroll
    for (int ks = 0; ks < 16; ++ks) {
      short8 bfrag = *(const short8*)(bp + ks * 32);
#pragma unroll
      for (int t = 0; t < 8; ++t) {
        int row = t * 16 + col;
        int byte = (row * 1024 + ks * 64 + kg * 16) ^ ((row & 7) << 4);
        short8 afrag = *(const short8*)((const char*)As + byte);
        acc[t] = __builtin_amdgcn_mfma_f32_16x16x32_bf16(afrag, bfrag, acc[t], 0, 0, 0);
      }
    }
#pragma unroll
    for (int t = 0; t < 8; ++t) {
      f32x4 v = acc[t];
      f32x4 mx = v;
#pragma unroll
      for (int d = 1; d < 16; d <<= 1) {
        mx.x = fmaxf(mx.x, __shfl_xor(mx.x, d));
        mx.y = fmaxf(mx.y, __shfl_xor(mx.y, d));
        mx.z = fmaxf(mx.z, __shfl_xor(mx.z, d));
        mx.w = fmaxf(mx.w, __shfl_xor(mx.w, d));
      }
      f32x4 nm;
      nm.x = fmaxf(rmax[t].x, mx.x);
      nm.y = fmaxf(rmax[t].y, mx.y);
      nm.z = fmaxf(rmax[t].z, mx.z);
      nm.w = fmaxf(rmax[t].w, mx.w);
      f32x4 e;
      e.x = __expf(v.x - nm.x); e.y = __expf(v.y - nm.y);
      e.z = __expf(v.z - nm.z); e.w = __expf(v.w - nm.w);
#pragma unroll
      for (int d = 1; d < 16; d <<= 1) {
        e.x += __shfl_xor(e.x, d);
        e.y += __shfl_xor(e.y, d);
        e.z += __shfl_xor(e.z, d);
        e.w += __shfl_xor(e.w, d);
      }
      rsum[t].x = rsum[t].x * __expf(rmax[t].x - nm.x) + e.x;
      rsum[t].y = rsum[t].y * __expf(rmax[t].y - nm.y) + e.y;
      rsum[t].z = rsum[t].z * __expf(rmax[t].z - nm.z) + e.z;
      rsum[t].w = rsum[t].w * __expf(rmax[t].w - nm.w) + e.w;
      rmax[t] = nm;
    }
  }
  if (col == 0) {
#pragma unroll
    for (int t = 0; t < 8; ++t) {
#pragma unroll
      for (int r = 0; r < 4; ++r) {
        int row = t * 16 + kg * 4 + r;
        sstat[(wv * 128 + row) * 2 + 0] = rmax[t][r];
        sstat[(wv * 128 + row) * 2 + 1] = rsum[t][r];
      }
    }
  }
  __syncthreads();
  if (tid < 128) {
    float m = -3.0e38f, ssum = 0.f;
#pragma unroll
    for (int w2 = 0; w2 < 4; ++w2) {
      float pm = sstat[(w2 * 128 + tid) * 2 + 0];
      float ps = sstat[(w2 * 128 + tid) * 2 + 1];
      float nm2 = fmaxf(m, pm);
      ssum = ssum * __expf(m - nm2) + ps * __expf(pm - nm2);
      m = nm2;
    }
    pmax[(size_t)(r0 + tid) * 16 + ch] = m;
    psum[(size_t)(r0 + tid) * 16 + ch] = ssum;
  }
}

// ---------------- target logit in f32: dot(h2[t], emb[tok[t]]) ----------------
__global__ __launch_bounds__(256) void k_tlogit(const int* __restrict__ tok,
                                                const float* __restrict__ emb,
                                                const float* __restrict__ h2buf,
                                                float* __restrict__ tlog) {
  const int wv = threadIdx.x >> 6, lane = threadIdx.x & 63;
  const int wgid = blockIdx.x * 4 + wv;
  for (int t = wgid; t < TSEQ; t += 128) {
    const float* hp = h2buf + (size_t)(t + 1) * DEMB + lane * 8;
    const float* ep = emb + (size_t)tok[t] * DEMB + lane * 8;
    float4 h0 = *(const float4*)hp, h1v = *(const float4*)(hp + 4);
    float4 e0 = *(const float4*)ep, e1v = *(const float4*)(ep + 4);
    float d = h0.x * e0.x + h0.y * e0.y + h0.z * e0.z + h0.w * e0.w +
              h1v.x * e1v.x + h1v.y * e1v.y + h1v.z * e1v.z + h1v.w * e1v.w;
    for (int m = 1; m < 64; m <<= 1) d += __shfl_xor(d, m);
    if (lane == 0) tlog[t] = d;
  }
}

// ---------------- final: sum_t (tlogit - lse) ----------------
__global__ void k_final(const float* __restrict__ pmax, const float* __restrict__ psum,
                        const float* __restrict__ tlog, float* __restrict__ out) {
  __shared__ float red[4];
  float local = 0.f;
  for (int t = threadIdx.x; t < TSEQ; t += 256) {
    float m = -3.0e38f, s = 0.f;
#pragma unroll
    for (int c = 0; c < 16; ++c) {
      float pm = pmax[t * 16 + c], ps = psum[t * 16 + c];
      float nm = fmaxf(m, pm);
      s = s * __expf(m - nm) + ps * __expf(pm - nm);
      m = nm;
    }
    local += tlog[t] - (m + __logf(s));
  }
  for (int d = 1; d < 64; d <<= 1) local += __shfl_xor(local, d);
  if ((threadIdx.x & 63) == 0) red[threadIdx.x >> 6] = local;
  __syncthreads();
  if (threadIdx.x == 0) out[0] = red[0] + red[1] + red[2] + red[3];
}

// ---------------- host ----------------
extern "C" void kernel_launch(void* const* d_in, const int* in_sizes, int n_in,
                              void* d_out, int out_size, void* d_ws, size_t ws_size,
                              hipStream_t stream) {
  (void)in_sizes; (void)n_in; (void)out_size; (void)ws_size;
  const int*   tok = (const int*)d_in[0];
  const float* emb = (const float*)d_in[1];
  const float* W1  = (const float*)d_in[2];
  const float* U1  = (const float*)d_in[3];
  const float* b1  = (const float*)d_in[4];
  const float* W2  = (const float*)d_in[5];
  const float* U2  = (const float*)d_in[6];
  const float* b2  = (const float*)d_in[7];
  float* out = (float*)d_out;

  char* ws = (char*)d_ws;
  size_t off = 0;
  auto alloc = [&](size_t bytes) {
    char* p = ws + off;
    off = (off + bytes + 255) & ~(size_t)255;
    return p;
  };
  float* h2buf = (float*)alloc((size_t)(TSEQ + 1) * DEMB * 4);
  unsigned short* h2b = (unsigned short*)alloc((size_t)TSEQ * DEMB * 2);
  float* pmax = (float*)alloc((size_t)TSEQ * 16 * 4);
  float* psum = (float*)alloc((size_t)TSEQ * 16 * 4);
  float* tlog = (float*)alloc((size_t)TSEQ * 4);
  // big region: [h2v][h1v][xW1] during k_rnn; embB (32.77MB) overlays from
  // offset 0 afterwards. Safe because k_init re-poisons all h slots at the
  // start of every launch before k_rnn runs.
  size_t sz_h2v = (size_t)(TSEQ + 1) * DEMB * 4;   //  4,196,352
  size_t sz_h1v = (size_t)(TSEQ + 1) * DHID * 4;   //  8,392,704
  size_t sz_xw1 = (size_t)TSEQ * DHID * 4;         //  8,388,608
  size_t sz_embB = (size_t)NVOCAB * DEMB * 2;      // 32,768,000
  size_t big_sz = sz_h2v + sz_h1v + sz_xw1;
  if (sz_embB > big_sz) big_sz = sz_embB;
  char* big = alloc(big_sz);
  float* h2v = (float*)big;
  float* h1v = (float*)(big + sz_h2v);
  float* xW1 = (float*)(big + sz_h2v + sz_h1v);
  unsigned short* embB = (unsigned short*)big;

  k_init<<<dim3(512), dim3(256), 0, stream>>>((uint4*)h1v, (uint4*)h2v);
  k_xw1<<<dim3(512), dim3(256), 0, stream>>>(tok, emb, W1, b1, xW1);
  k_rnn<<<dim3(96), dim3(256), 0, stream>>>(xW1, U1, W2, U2, b2, h1v, h2v, h2buf);
  k_conv<<<dim3(2048), dim3(256), 0, stream>>>(emb, h2buf + DEMB, embB, h2b);
  k_logits<<<dim3(256), dim3(256), 135168, stream>>>(h2b, embB, pmax, psum);
  k_tlogit<<<dim3(32), dim3(256), 0, stream>>>(tok, emb, h2buf, tlog);
  k_final<<<dim3(1), dim3(256), 0, stream>>>(pmax, psum, tlog, out);
}

// Round 12
// 3855.729 us; speedup vs baseline: 1.3404x; 1.3404x over previous
//
#include <hip/hip_runtime.h>
#include <stdint.h>

// RNN LM: embed->shift -> 2-layer tanh RNN (T=2048) -> logits vs embedding^T
//         -> log_softmax -> gather at tokens -> sum (scalar out).
//
// k_rnn R12: R6 EXACT (f32 canary dataflow, fused wide-load polls, DPP-ring
// dots, s_barrier combine) + PACKED producer stores: finalize runs on all of
// wave 0 (shfls unconditional), lanes 0/4/8/12 store one dwordx4 sc0 sc1
// covering 4 cols = exactly one consumer poll-quad. Eliminates the
// partial-arrival poll rounds caused by 16 independent dword stores filling
// one cache line, and cuts store transactions 4x.

#define TSEQ 2048
#define NVOCAB 32000
#define DEMB 512
#define DHID 1024
#define CAN 0xFFFFFFFFu

typedef __attribute__((ext_vector_type(8))) short short8;
typedef __attribute__((ext_vector_type(4))) float f32x4;
typedef __attribute__((ext_vector_type(2))) float f32x2;

__device__ __forceinline__ unsigned short f2bf(float f) {
  union { float f; unsigned u; } v; v.f = f;
  unsigned r = (v.u + 0x7FFFu + ((v.u >> 16) & 1u)) >> 16;
  return (unsigned short)r;
}

__device__ __forceinline__ f32x4 llc_ld16(const float* p) {
  f32x4 r;
  asm volatile("global_load_dwordx4 %0, %1, off sc0 sc1\n\ts_waitcnt vmcnt(0)"
               : "=&v"(r) : "v"(p) : "memory");
  return r;
}

// dwordx4 + dwordx2 from two bases, single waitcnt (fused, safe).
__device__ __forceinline__ void llc_ld16_8(const float* pa, const float* pb,
                                           f32x4& a, f32x2& b) {
  asm volatile("global_load_dwordx4 %0, %2, off sc0 sc1\n\t"
               "global_load_dwordx2 %1, %3, off sc0 sc1\n\t"
               "s_waitcnt vmcnt(0)"
               : "=&v"(a), "=&v"(b) : "v"(pa), "v"(pb) : "memory");
}

__device__ __forceinline__ void llc_st16(float* p, f32x4 v) {
  asm volatile("global_store_dwordx4 %0, %1, off sc0 sc1"
               :: "v"(p), "v"(v) : "memory");
}

__device__ __forceinline__ bool okq4(f32x4 v) {
  return (__float_as_uint(v.x) != CAN) & (__float_as_uint(v.y) != CAN) &
         (__float_as_uint(v.z) != CAN) & (__float_as_uint(v.w) != CAN);
}
__device__ __forceinline__ bool okp2(f32x2 v) {
  return (__float_as_uint(v.x) != CAN) & (__float_as_uint(v.y) != CAN);
}

// rotate right by 1 lane within each 16-lane row (row_ror:1 = 0x121)
__device__ __forceinline__ f32x4 rotq(f32x4 h) {
  f32x4 r;
  r.x = __int_as_float(__builtin_amdgcn_mov_dpp(__float_as_int(h.x), 0x121, 0xf, 0xf, false));
  r.y = __int_as_float(__builtin_amdgcn_mov_dpp(__float_as_int(h.y), 0x121, 0xf, 0xf, false));
  r.z = __int_as_float(__builtin_amdgcn_mov_dpp(__float_as_int(h.z), 0x121, 0xf, 0xf, false));
  r.w = __int_as_float(__builtin_amdgcn_mov_dpp(__float_as_int(h.w), 0x121, 0xf, 0xf, false));
  return r;
}
__device__ __forceinline__ f32x2 rotp(f32x2 h) {
  f32x2 r;
  r.x = __int_as_float(__builtin_amdgcn_mov_dpp(__float_as_int(h.x), 0x121, 0xf, 0xf, false));
  r.y = __int_as_float(__builtin_amdgcn_mov_dpp(__float_as_int(h.y), 0x121, 0xf, 0xf, false));
  return r;
}

__device__ __forceinline__ float tanh_fast(float x) {
  float ax = fabsf(x);
  float e = __expf(ax + ax);
  float t = 1.f - __fdividef(2.f, e + 1.f);
  return (x < 0.f) ? -t : t;
}

// ---------------- init: poison all slots; row 0 = real zeros ----------------
__global__ void k_init(uint4* __restrict__ h1v4, uint4* __restrict__ h2v4) {
  const int n1 = (TSEQ + 1) * DHID / 4;
  const int n2 = (TSEQ + 1) * DEMB / 4;
  uint4 can; can.x = CAN; can.y = CAN; can.z = CAN; can.w = CAN;
  uint4 zer; zer.x = 0u; zer.y = 0u; zer.z = 0u; zer.w = 0u;
  const int stride = gridDim.x * blockDim.x;
  for (int i = blockIdx.x * blockDim.x + threadIdx.x; i < n1 + n2; i += stride) {
    if (i < n1) {
      h1v4[i] = (i < DHID / 4) ? zer : can;
    } else {
      int j = i - n1;
      h2v4[j] = (j < DEMB / 4) ? zer : can;
    }
  }
}

// ---------------- xW1[t][j] = b1[j] + sum_e inputs[t][e]*W1[e][j] ------------
__global__ __launch_bounds__(256) void k_xw1(const int* __restrict__ tok,
                                             const float* __restrict__ emb,
                                             const float* __restrict__ W1,
                                             const float* __restrict__ b1,
                                             float* __restrict__ xW1) {
  __shared__ float in_lds[16 * DEMB];
  const int tid = threadIdx.x;
  const int rb = blockIdx.x >> 2, cb = blockIdx.x & 3;
  const int t0 = rb * 16, j0 = cb * 256;
  for (int idx = tid; idx < 16 * 128; idx += 256) {
    int r = idx >> 7, q = idx & 127;
    int t = t0 + r;
    float4 v;
    if (t == 0) { v.x = 0.f; v.y = 0.f; v.z = 0.f; v.w = 0.f; }
    else        { v = *(const float4*)(emb + (size_t)tok[t - 1] * DEMB + q * 4); }
    *(float4*)&in_lds[r * DEMB + q * 4] = v;
  }
  __syncthreads();
  const int j = j0 + tid;
  float acc[16];
  {
    float bb = b1[j];
#pragma unroll
    for (int r = 0; r < 16; ++r) acc[r] = bb;
  }
  for (int k = 0; k < DEMB; k += 4) {
    const float* wp = W1 + (size_t)k * DHID + j;
    float w0 = wp[0], w1 = wp[DHID], w2 = wp[2 * DHID], w3 = wp[3 * DHID];
#pragma unroll
    for (int r = 0; r < 16; ++r) {
      float4 h = *(const float4*)&in_lds[r * DEMB + k];
      acc[r] += h.x * w0;
      acc[r] += h.y * w1;
      acc[r] += h.z * w2;
      acc[r] += h.w * w3;
    }
  }
#pragma unroll
  for (int r = 0; r < 16; ++r) xW1[(size_t)(t0 + r) * DHID + j] = acc[r];
}

// ---------------- persistent RNN ----------------
// 96 WGs x 256 thr. WG 0..63: layer1 (16 cols). WG 64..95: layer2 (16 cols).
__global__ __launch_bounds__(256, 1) void k_rnn(const float* __restrict__ xW1,
                                                const float* __restrict__ U1,
                                                const float* __restrict__ W2,
                                                const float* __restrict__ U2,
                                                const float* __restrict__ b2,
                                                float* __restrict__ h1v,
                                                float* __restrict__ h2v,
                                                float* __restrict__ h2buf) {
  __shared__ float cmb[2][128];   // [parity][col*8 + wave]
  const int tid = threadIdx.x;
  const int wg = blockIdx.x;
  const int l = tid & 63, w = tid >> 6;
  const int r = l >> 4, i = l & 15;

  if (wg < 64) {  // ---- layer 1: h1[t] = tanh(xW1[t] + h1[t-1]@U1) ----
    const int c0 = wg * 16;
    // wA[4j+e] = U1[256w + 64r + 4*((i-j)&15) + e][c0+i]
    float wA[64];
#pragma unroll
    for (int j = 0; j < 16; ++j) {
      int sl = (i - j) & 15;
      const float* up = U1 + (size_t)(256 * w + 64 * r + 4 * sl) * DHID + c0 + i;
#pragma unroll
      for (int e = 0; e < 4; ++e) wA[4 * j + e] = up[(size_t)e * DHID];
    }
    const float* pp = h1v + 4 * tid;              // poll row st (st=0 -> zeros)
    const float* xp = xW1 + c0 + (tid & 15);
    float* stp = h1v + DHID + c0 + l;             // store row st+1 (lanes 0,4,8,12)
    for (int st = 0; st < TSEQ; ++st) {
      float xv = *xp;                             // early, independent
      f32x4 h;
      while (true) { h = llc_ld16(pp); if (okq4(h)) break; }
      f32x4 ac = (f32x4)(0.f);
#pragma unroll
      for (int j = 0; j < 16; ++j) {
        ac.x += h.x * wA[4 * j + 0];
        ac.y += h.y * wA[4 * j + 1];
        ac.z += h.z * wA[4 * j + 2];
        ac.w += h.w * wA[4 * j + 3];
        if (j < 15) h = rotq(h);
      }
      float a = (ac.x + ac.y) + (ac.z + ac.w);
      a += __shfl_xor(a, 16);
      a += __shfl_xor(a, 32);
      const int par = st & 1;
      if (l < 16) cmb[par][i * 8 + w] = a;
      __syncthreads();
      if (w == 0) {                               // finalize on full wave 0
        f32x4 c4 = *(const f32x4*)&cmb[par][(l & 15) * 8];
        float hv = tanh_fast(xv + ((c4.x + c4.y) + (c4.z + c4.w)));
        float g1 = __shfl_down(hv, 1);            // unconditional shfls
        float g2 = __shfl_down(hv, 2);
        float g3 = __shfl_down(hv, 3);
        if (l < 16 && (l & 3) == 0) {             // one dwordx4 per 4 cols
          f32x4 o; o.x = hv; o.y = g1; o.z = g2; o.w = g3;
          llc_st16(stp, o);
        }
      }
      pp += DHID; xp += DHID; stp += DHID;
    }
  } else {  // ---- layer 2: h2[t] = tanh(h1[t]@W2 + h2[t-1]@U2 + b2) ----
    const int c0 = (wg - 64) * 16;
    // quad-ring (W2, 64 k of h1) + pair-ring (U2, 32 k of h2prev)
    float wq[64], wp[32];
#pragma unroll
    for (int j = 0; j < 16; ++j) {
      int sl = (i - j) & 15;
      const float* m = W2 + (size_t)(256 * w + 64 * r + 4 * sl) * DEMB + c0 + i;
#pragma unroll
      for (int e = 0; e < 4; ++e) wq[4 * j + e] = m[(size_t)e * DEMB];
      const float* u = U2 + (size_t)(128 * w + 32 * r + 2 * sl) * DEMB + c0 + i;
      wp[2 * j + 0] = u[0];
      wp[2 * j + 1] = u[DEMB];
    }
    const float bias = b2[c0 + (tid & 15)];
    const float* ppA = h1v + DHID + 256 * w + 64 * r + 4 * i;  // h1[t] = row t+1
    const float* ppB = h2v + 128 * w + 32 * r + 2 * i;         // h2[t-1] = row t
    float* stp = h2v + DEMB + c0 + l;             // row t+1 (lanes 0,4,8,12)
    float* hb = h2buf + DEMB + c0 + l;
    for (int t = 0; t < TSEQ; ++t) {
      f32x4 hq; f32x2 hp;
      while (true) {
        llc_ld16_8(ppA, ppB, hq, hp);
        if (okq4(hq) & okp2(hp)) break;
      }
      f32x4 aq = (f32x4)(0.f);
      f32x2 ap = (f32x2)(0.f);
#pragma unroll
      for (int j = 0; j < 16; ++j) {
        aq.x += hq.x * wq[4 * j + 0];
        aq.y += hq.y * wq[4 * j + 1];
        aq.z += hq.z * wq[4 * j + 2];
        aq.w += hq.w * wq[4 * j + 3];
        ap.x += hp.x * wp[2 * j + 0];
        ap.y += hp.y * wp[2 * j + 1];
        if (j < 15) { hq = rotq(hq); hp = rotp(hp); }
      }
      float a = ((aq.x + aq.y) + (aq.z + aq.w)) + (ap.x + ap.y);
      a += __shfl_xor(a, 16);
      a += __shfl_xor(a, 32);
      const int par = t & 1;
      if (l < 16) cmb[par][i * 8 + w] = a;
      __syncthreads();
      if (w == 0) {                               // finalize on full wave 0
        f32x4 c4 = *(const f32x4*)&cmb[par][(l & 15) * 8];
        float hv = tanh_fast(bias + ((c4.x + c4.y) + (c4.z + c4.w)));
        float g1 = __shfl_down(hv, 1);            // unconditional shfls
        float g2 = __shfl_down(hv, 2);
        float g3 = __shfl_down(hv, 3);
        if (l < 16 && (l & 3) == 0) {
          f32x4 o; o.x = hv; o.y = g1; o.z = g2; o.w = g3;
          llc_st16(stp, o);
          *(f32x4*)hb = o;                        // f32 history for logits path
        }
      }
      ppA += DHID; ppB += DEMB; stp += DEMB; hb += DEMB;
    }
  }
}

// ---------------- f32 -> bf16 casts (embedding + h2 history) ----------------
__global__ void k_conv(const float* __restrict__ emb, const float* __restrict__ h2f,
                       unsigned short* __restrict__ embB, unsigned short* __restrict__ h2b) {
  const int n1 = NVOCAB * DEMB / 4;
  const int n2 = TSEQ * DEMB / 4;
  const int stride = gridDim.x * blockDim.x;
  for (int i = blockIdx.x * blockDim.x + threadIdx.x; i < n1 + n2; i += stride) {
    float4 v;
    if (i < n1) v = ((const float4*)emb)[i];
    else        v = ((const float4*)h2f)[i - n1];
    ushort4 o;
    o.x = f2bf(v.x); o.y = f2bf(v.y); o.z = f2bf(v.z); o.w = f2bf(v.w);
    if (i < n1) ((ushort4*)embB)[i] = o;
    else        ((ushort4*)h2b)[i - n1] = o;
  }
}

// ---------------- fused logits GEMM + online softmax stats ----------------
__global__ __launch_bounds__(256, 1) void k_logits(const unsigned short* __restrict__ Ab,
                                                   const unsigned short* __restrict__ Bb,
                                                   float* __restrict__ pmax,
                                                   float* __restrict__ psum) {
  extern __shared__ char smem_dyn[];
  unsigned short* As = (unsigned short*)smem_dyn;       // 128*512*2 = 131072 B
  float* sstat = (float*)(smem_dyn + 131072);           // 4*128*2 f32
  const int tid = threadIdx.x;
  const int rb = blockIdx.x >> 4, ch = blockIdx.x & 15;
  const int r0 = rb * 128, v0 = ch * 2000;
  for (int idx = tid; idx < 128 * 64; idx += 256) {
    int row = idx >> 6, kq = idx & 63;
    uint4 v = *(const uint4*)(Ab + (size_t)(r0 + row) * DEMB + kq * 8);
    int byte = (row * 1024 + kq * 16) ^ ((row & 7) << 4);
    *(uint4*)((char*)As + byte) = v;
  }
  __syncthreads();
  const int wv = tid >> 6, lane = tid & 63;
  const int col = lane & 15, kg = lane >> 4;
  f32x4 rmax[8], rsum[8];
#pragma unroll
  for (int t = 0; t < 8; ++t) { rmax[t] = (f32x4)(-3.0e38f); rsum[t] = (f32x4)(0.f); }

  for (int strip = wv; strip < 125; strip += 4) {
    const unsigned short* bp = Bb + (size_t)(v0 + strip * 16 + col) * DEMB + kg * 8;
    f32x4 acc[8];
#pragma unroll
    for (int t = 0; t < 8; ++t) acc[t] = (f32x4)(0.f);
#pragma unroll
    for (int ks = 0; ks < 16; ++ks) {
      short8 bfrag = *(const short8*)(bp + ks * 32);
#pragma unroll
      for (int t = 0; t < 8; ++t) {
        int row = t * 16 + col;
        int byte = (row * 1024 + ks * 64 + kg * 16) ^ ((row & 7) << 4);
        short8 afrag = *(const short8*)((const char*)As + byte);
        acc[t] = __builtin_amdgcn_mfma_f32_16x16x32_bf16(afrag, bfrag, acc[t], 0, 0, 0);
      }
    }
#pragma unroll
    for (int t = 0; t < 8; ++t) {
      f32x4 v = acc[t];
      f32x4 mx = v;
#pragma unroll
      for (int d = 1; d < 16; d <<= 1) {
        mx.x = fmaxf(mx.x, __shfl_xor(mx.x, d));
        mx.y = fmaxf(mx.y, __shfl_xor(mx.y, d));
        mx.z = fmaxf(mx.z, __shfl_xor(mx.z, d));
        mx.w = fmaxf(mx.w, __shfl_xor(mx.w, d));
      }
      f32x4 nm;
      nm.x = fmaxf(rmax[t].x, mx.x);
      nm.y = fmaxf(rmax[t].y, mx.y);
      nm.z = fmaxf(rmax[t].z, mx.z);
      nm.w = fmaxf(rmax[t].w, mx.w);
      f32x4 e;
      e.x = __expf(v.x - nm.x); e.y = __expf(v.y - nm.y);
      e.z = __expf(v.z - nm.z); e.w = __expf(v.w - nm.w);
#pragma unroll
      for (int d = 1; d < 16; d <<= 1) {
        e.x += __shfl_xor(e.x, d);
        e.y += __shfl_xor(e.y, d);
        e.z += __shfl_xor(e.z, d);
        e.w += __shfl_xor(e.w, d);
      }
      rsum[t].x = rsum[t].x * __expf(rmax[t].x - nm.x) + e.x;
      rsum[t].y = rsum[t].y * __expf(rmax[t].y - nm.y) + e.y;
      rsum[t].z = rsum[t].z * __expf(rmax[t].z - nm.z) + e.z;
      rsum[t].w = rsum[t].w * __expf(rmax[t].w - nm.w) + e.w;
      rmax[t] = nm;
    }
  }
  if (col == 0) {
#pragma unroll
    for (int t = 0; t < 8; ++t) {
#pragma unroll
      for (int r = 0; r < 4; ++r) {
        int row = t * 16 + kg * 4 + r;
        sstat[(wv * 128 + row) * 2 + 0] = rmax[t][r];
        sstat[(wv * 128 + row) * 2 + 1] = rsum[t][r];
      }
    }
  }
  __syncthreads();
  if (tid < 128) {
    float m = -3.0e38f, ssum = 0.f;
#pragma unroll
    for (int w2 = 0; w2 < 4; ++w2) {
      float pm = sstat[(w2 * 128 + tid) * 2 + 0];
      float ps = sstat[(w2 * 128 + tid) * 2 + 1];
      float nm2 = fmaxf(m, pm);
      ssum = ssum * __expf(m - nm2) + ps * __expf(pm - nm2);
      m = nm2;
    }
    pmax[(size_t)(r0 + tid) * 16 + ch] = m;
    psum[(size_t)(r0 + tid) * 16 + ch] = ssum;
  }
}

// ---------------- target logit in f32: dot(h2[t], emb[tok[t]]) ----------------
__global__ __launch_bounds__(256) void k_tlogit(const int* __restrict__ tok,
                                                const float* __restrict__ emb,
                                                const float* __restrict__ h2buf,
                                                float* __restrict__ tlog) {
  const int wv = threadIdx.x >> 6, lane = threadIdx.x & 63;
  const int wgid = blockIdx.x * 4 + wv;
  for (int t = wgid; t < TSEQ; t += 128) {
    const float* hp = h2buf + (size_t)(t + 1) * DEMB + lane * 8;
    const float* ep = emb + (size_t)tok[t] * DEMB + lane * 8;
    float4 h0 = *(const float4*)hp, h1v = *(const float4*)(hp + 4);
    float4 e0 = *(const float4*)ep, e1v = *(const float4*)(ep + 4);
    float d = h0.x * e0.x + h0.y * e0.y + h0.z * e0.z + h0.w * e0.w +
              h1v.x * e1v.x + h1v.y * e1v.y + h1v.z * e1v.z + h1v.w * e1v.w;
    for (int m = 1; m < 64; m <<= 1) d += __shfl_xor(d, m);
    if (lane == 0) tlog[t] = d;
  }
}

// ---------------- final: sum_t (tlogit - lse) ----------------
__global__ void k_final(const float* __restrict__ pmax, const float* __restrict__ psum,
                        const float* __restrict__ tlog, float* __restrict__ out) {
  __shared__ float red[4];
  float local = 0.f;
  for (int t = threadIdx.x; t < TSEQ; t += 256) {
    float m = -3.0e38f, s = 0.f;
#pragma unroll
    for (int c = 0; c < 16; ++c) {
      float pm = pmax[t * 16 + c], ps = psum[t * 16 + c];
      float nm = fmaxf(m, pm);
      s = s * __expf(m - nm) + ps * __expf(pm - nm);
      m = nm;
    }
    local += tlog[t] - (m + __logf(s));
  }
  for (int d = 1; d < 64; d <<= 1) local += __shfl_xor(local, d);
  if ((threadIdx.x & 63) == 0) red[threadIdx.x >> 6] = local;
  __syncthreads();
  if (threadIdx.x == 0) out[0] = red[0] + red[1] + red[2] + red[3];
}

// ---------------- host ----------------
extern "C" void kernel_launch(void* const* d_in, const int* in_sizes, int n_in,
                              void* d_out, int out_size, void* d_ws, size_t ws_size,
                              hipStream_t stream) {
  (void)in_sizes; (void)n_in; (void)out_size; (void)ws_size;
  const int*   tok = (const int*)d_in[0];
  const float* emb = (const float*)d_in[1];
  const float* W1  = (const float*)d_in[2];
  const float* U1  = (const float*)d_in[3];
  const float* b1  = (const float*)d_in[4];
  const float* W2  = (const float*)d_in[5];
  const float* U2  = (const float*)d_in[6];
  const float* b2  = (const float*)d_in[7];
  float* out = (float*)d_out;

  char* ws = (char*)d_ws;
  size_t off = 0;
  auto alloc = [&](size_t bytes) {
    char* p = ws + off;
    off = (off + bytes + 255) & ~(size_t)255;
    return p;
  };
  float* h2buf = (float*)alloc((size_t)(TSEQ + 1) * DEMB * 4);
  unsigned short* h2b = (unsigned short*)alloc((size_t)TSEQ * DEMB * 2);
  float* pmax = (float*)alloc((size_t)TSEQ * 16 * 4);
  float* psum = (float*)alloc((size_t)TSEQ * 16 * 4);
  float* tlog = (float*)alloc((size_t)TSEQ * 4);
  // big region: [h2v][h1v][xW1] during k_rnn; embB (32.77MB) overlays from
  // offset 0 afterwards. Safe because k_init re-poisons all h slots at the
  // start of every launch before k_rnn runs.
  size_t sz_h2v = (size_t)(TSEQ + 1) * DEMB * 4;   //  4,196,352
  size_t sz_h1v = (size_t)(TSEQ + 1) * DHID * 4;   //  8,392,704
  size_t sz_xw1 = (size_t)TSEQ * DHID * 4;         //  8,388,608
  size_t sz_embB = (size_t)NVOCAB * DEMB * 2;      // 32,768,000
  size_t big_sz = sz_h2v + sz_h1v + sz_xw1;
  if (sz_embB > big_sz) big_sz = sz_embB;
  char* big = alloc(big_sz);
  float* h2v = (float*)big;
  float* h1v = (float*)(big + sz_h2v);
  float* xW1 = (float*)(big + sz_h2v + sz_h1v);
  unsigned short* embB = (unsigned short*)big;

  k_init<<<dim3(512), dim3(256), 0, stream>>>((uint4*)h1v, (uint4*)h2v);
  k_xw1<<<dim3(512), dim3(256), 0, stream>>>(tok, emb, W1, b1, xW1);
  k_rnn<<<dim3(96), dim3(256), 0, stream>>>(xW1, U1, W2, U2, b2, h1v, h2v, h2buf);
  k_conv<<<dim3(2048), dim3(256), 0, stream>>>(emb, h2buf + DEMB, embB, h2b);
  k_logits<<<dim3(256), dim3(256), 135168, stream>>>(h2b, embB, pmax, psum);
  k_tlogit<<<dim3(32), dim3(256), 0, stream>>>(tok, emb, h2buf, tlog);
  k_final<<<dim3(1), dim3(256), 0, stream>>>(pmax, psum, tlog, out);
}